// Round 10
// baseline (430.090 us; speedup 1.0000x reference)
//
#include <hip/hip_runtime.h>

typedef unsigned short ushort_t;
typedef __attribute__((ext_vector_type(8))) short bf16x8;
typedef __attribute__((ext_vector_type(4))) float f32x4;
typedef __attribute__((ext_vector_type(4))) unsigned short u16x4;

#define T_DIM 2048
#define D_DIM 512
#define NH 8
#define NB 2
// S is stored tile-packed: per (batch,head), 136 causal tiles of 128x128 fp32
// (64KB slots). Slot index for tile (tq,ts) = tq*(tq+1)/2 + ts.
#define SLOT_F 16384          // fp32 elems per slot (128*128)

static __device__ __forceinline__ ushort_t f2bf(float x) {
  union { float f; unsigned u; } v; v.f = x;
  unsigned r = v.u + 0x7fffu + ((v.u >> 16) & 1u);
  return (ushort_t)(r >> 16);
}
static __device__ __forceinline__ float bf2f(ushort_t b) {
  union { unsigned u; float f; } v; v.u = ((unsigned)b) << 16;
  return v.f;
}
static __device__ __forceinline__ f32x4 mfma16(bf16x8 a, bf16x8 b, f32x4 c) {
  return __builtin_amdgcn_mfma_f32_16x16x32_bf16(a, b, c, 0, 0, 0);
}

typedef const __attribute__((address_space(1))) unsigned asg_t;
typedef __attribute__((address_space(3))) unsigned asl_t;
static __device__ __forceinline__ void gload16(const ushort_t* g, ushort_t* l) {
  __builtin_amdgcn_global_load_lds((asg_t*)g, (asl_t*)l, 16, 0, 0);
}

// stage a [128][32] bf16 tile (8KB) from global rows (stride ldk) into LDS.
static __device__ __forceinline__ void stage128x32(const ushort_t* __restrict__ src,
                                                   size_t ldk, ushort_t* lds, int tid) {
  int w = tid >> 6;
#pragma unroll
  for (int p = 0; p < 2; ++p) {
    int t = p * 256 + tid;          // 512 chunks of 8 elems
    int r = t >> 2;                 // row 0..127
    int col = (t & 3) << 3;         // 0,8,16,24
    gload16(src + (size_t)r * ldk + col, lds + p * 2048 + (w << 9));
  }
}

// decode fastest grid index j (0..8*nbc-1) -> (bl, hd): head<->XCD affinity.
static __device__ __forceinline__ void decode_bh(int j, int nbc, int& bl, int& hd) {
  if (nbc == 2) { bl = j & 1; hd = j >> 1; } else { bl = 0; hd = j; }
}

// ---------------- split h -> h_hi/h_lo (bf16) + hT (bf16 transpose) ----------------
__global__ __launch_bounds__(256) void split_h_kernel(const float* __restrict__ h,
    ushort_t* __restrict__ hhi, ushort_t* __restrict__ hlo, ushort_t* __restrict__ hT) {
  __shared__ ushort_t lds[64][68];
  int x = blockIdx.x;                 // 512 = b(2) x tt(32) x ee(8)
  int b = x >> 8, tt = (x >> 3) & 31, ee = x & 7;
  int t0 = tt * 64, e0 = ee * 64;
  int rr = threadIdx.x >> 4;
  int c4 = (threadIdx.x & 15) * 4;
#pragma unroll
  for (int it = 0; it < 4; ++it) {
    int t = it * 16 + rr;
    size_t idx = ((size_t)(b * T_DIM + t0 + t)) * D_DIM + e0 + c4;
    float4 v = *(const float4*)(h + idx);
    u16x4 hv, lv;
    hv[0] = f2bf(v.x); lv[0] = f2bf(v.x - bf2f(hv[0]));
    hv[1] = f2bf(v.y); lv[1] = f2bf(v.y - bf2f(hv[1]));
    hv[2] = f2bf(v.z); lv[2] = f2bf(v.z - bf2f(hv[2]));
    hv[3] = f2bf(v.w); lv[3] = f2bf(v.w - bf2f(hv[3]));
    *(u16x4*)(hhi + idx) = hv;
    *(u16x4*)(hlo + idx) = lv;
    *(u16x4*)&lds[t][c4] = hv;
  }
  __syncthreads();
#pragma unroll
  for (int it = 0; it < 4; ++it) {
    int e = it * 16 + rr;
    u16x4 wv;
    wv[0] = lds[c4 + 0][e];
    wv[1] = lds[c4 + 1][e];
    wv[2] = lds[c4 + 2][e];
    wv[3] = lds[c4 + 3][e];
    *(u16x4*)(hT + ((size_t)(b * D_DIM + e0 + e)) * T_DIM + t0 + c4) = wv;
  }
}

// ---------------- split+transpose A -> AT_hi/AT_lo ([head][e][d], d contiguous) ----
__global__ __launch_bounds__(256) void split_AT_kernel(const float* __restrict__ A,
    ushort_t* __restrict__ AThi, ushort_t* __restrict__ ATlo) {
  __shared__ ushort_t ldh[64][68];
  __shared__ ushort_t ldl[64][68];
  int x = blockIdx.x;                 // 512 = head(8) x dd(8) x ee(8)
  int hd = x >> 6, dd = (x >> 3) & 7, ee = x & 7;
  int d0 = dd * 64, e0 = ee * 64;
  int rr = threadIdx.x >> 4;
  int c4 = (threadIdx.x & 15) * 4;
#pragma unroll
  for (int it = 0; it < 4; ++it) {
    int d = it * 16 + rr;
    float4 v = *(const float4*)(A + ((size_t)(hd * D_DIM + d0 + d)) * D_DIM + e0 + c4);
    u16x4 hv, lv;
    hv[0] = f2bf(v.x); lv[0] = f2bf(v.x - bf2f(hv[0]));
    hv[1] = f2bf(v.y); lv[1] = f2bf(v.y - bf2f(hv[1]));
    hv[2] = f2bf(v.z); lv[2] = f2bf(v.z - bf2f(hv[2]));
    hv[3] = f2bf(v.w); lv[3] = f2bf(v.w - bf2f(hv[3]));
    *(u16x4*)&ldh[d][c4] = hv;
    *(u16x4*)&ldl[d][c4] = lv;
  }
  __syncthreads();
#pragma unroll
  for (int it = 0; it < 4; ++it) {
    int e = it * 16 + rr;
    u16x4 wh, wl;
    wh[0] = ldh[c4 + 0][e]; wl[0] = ldl[c4 + 0][e];
    wh[1] = ldh[c4 + 1][e]; wl[1] = ldl[c4 + 1][e];
    wh[2] = ldh[c4 + 2][e]; wl[2] = ldl[c4 + 2][e];
    wh[3] = ldh[c4 + 3][e]; wl[3] = ldl[c4 + 3][e];
    size_t o = ((size_t)(hd * D_DIM + e0 + e)) * D_DIM + d0 + c4;
    *(u16x4*)(AThi + o) = wh;
    *(u16x4*)(ATlo + o) = wl;
  }
}

// ---------------- Q-GEMM: Q[b,hd] = h_b @ A_hd (split x3), 1-buffer staging --------
__global__ __launch_bounds__(256, 2) void qgemm_kernel(
    const ushort_t* __restrict__ hhi, const ushort_t* __restrict__ hlo,
    const ushort_t* __restrict__ AThi, const ushort_t* __restrict__ ATlo,
    ushort_t* __restrict__ Qhi, ushort_t* __restrict__ Qlo) {
  __shared__ ushort_t lAh[128 * 32], lAl[128 * 32], lBh[128 * 32], lBl[128 * 32];
  int bid = blockIdx.x;               // 1024 = mt(16) x nt(4) x b(2) x hd(8), hd fastest
  int hd = bid & 7;
  int rem = bid >> 3;
  int nt = rem & 3;
  int mt = (rem >> 2) & 15;
  int b = rem >> 6;
  int bh = b * NH + hd;
  int tid = threadIdx.x;
  int w = tid >> 6, lane = tid & 63;
  int g = lane >> 4, c = lane & 15;
  int m0 = (w >> 1) * 64, n0 = (w & 1) * 64;
  const ushort_t* Ah = hhi + (size_t)b * T_DIM * D_DIM + (size_t)(mt * 128) * D_DIM;
  const ushort_t* Al = hlo + (size_t)b * T_DIM * D_DIM + (size_t)(mt * 128) * D_DIM;
  const ushort_t* Bh = AThi + (size_t)hd * D_DIM * D_DIM + (size_t)(nt * 128) * D_DIM;
  const ushort_t* Bl = ATlo + (size_t)hd * D_DIM * D_DIM + (size_t)(nt * 128) * D_DIM;
  f32x4 zero4 = {0.f, 0.f, 0.f, 0.f};
  f32x4 acc[4][4];
#pragma unroll
  for (int i = 0; i < 4; ++i)
#pragma unroll
    for (int j = 0; j < 4; ++j) acc[i][j] = zero4;
  for (int kc = 0; kc < 16; ++kc) {
    int k0 = kc * 32;
    stage128x32(Ah + k0, D_DIM, lAh, tid);
    stage128x32(Al + k0, D_DIM, lAl, tid);
    stage128x32(Bh + k0, D_DIM, lBh, tid);
    stage128x32(Bl + k0, D_DIM, lBl, tid);
    __syncthreads();
    bf16x8 ah[4], al[4], bh8[4], bl8[4];
#pragma unroll
    for (int mf = 0; mf < 4; ++mf) {
      int ro = (m0 + 16 * mf + c) * 32 + g * 8;
      ah[mf] = *(const bf16x8*)&lAh[ro];
      al[mf] = *(const bf16x8*)&lAl[ro];
    }
#pragma unroll
    for (int nf = 0; nf < 4; ++nf) {
      int ro = (n0 + 16 * nf + c) * 32 + g * 8;
      bh8[nf] = *(const bf16x8*)&lBh[ro];
      bl8[nf] = *(const bf16x8*)&lBl[ro];
    }
#pragma unroll
    for (int mf = 0; mf < 4; ++mf)
#pragma unroll
      for (int nf = 0; nf < 4; ++nf) {
        acc[mf][nf] = mfma16(ah[mf], bh8[nf], acc[mf][nf]);
        acc[mf][nf] = mfma16(ah[mf], bl8[nf], acc[mf][nf]);
        acc[mf][nf] = mfma16(al[mf], bh8[nf], acc[mf][nf]);
      }
    __syncthreads();
  }
  size_t qbase = (size_t)bh * T_DIM * D_DIM;
#pragma unroll
  for (int mf = 0; mf < 4; ++mf)
#pragma unroll
    for (int nf = 0; nf < 4; ++nf)
#pragma unroll
      for (int i2 = 0; i2 < 4; ++i2) {
        int q = mt * 128 + m0 + 16 * mf + 4 * g + i2;
        int e = nt * 128 + n0 + 16 * nf + c;
        float v = acc[mf][nf][i2];
        ushort_t hi = f2bf(v);
        ushort_t lo = f2bf(v - bf2f(hi));
        Qhi[qbase + (size_t)q * D_DIM + e] = hi;
        Qlo[qbase + (size_t)q * D_DIM + e] = lo;
      }
}

// ---------------- S-GEMM: causal tiles, S = Q @ K^T (split x3) + row-tile stats ----
// Writes tile-packed S slots + per-tile row max (statm) and expsum (statl).
// Diagonal tiles masked (col>row) in the stats; S itself keeps garbage there
// (never read by pv thanks to the same mask).
__global__ __launch_bounds__(256, 2) void sgemm_kernel(
    const ushort_t* __restrict__ Qhi, const ushort_t* __restrict__ Qlo,
    const ushort_t* __restrict__ Khi, const ushort_t* __restrict__ Klo,
    float* __restrict__ S, float* __restrict__ statm, float* __restrict__ statl,
    int b0, int nbc) {
  __shared__ ushort_t lAh[128 * 32], lAl[128 * 32], lBh[128 * 32], lBl[128 * 32];
  int mlanes = nbc * 8;
  int i = blockIdx.x;                 // (nbc*8) bh (fastest) x 136 lower-tri tiles
  int j = i % mlanes, ti = i / mlanes;
  int bl, hd;
  decode_bh(j, nbc, bl, hd);
  int b = b0 + bl;
  int bh = b * NH + hd;
  int bhl = bl * NH + hd;
  int tq = (int)((sqrtf(8.f * (float)ti + 1.f) - 1.f) * 0.5f);
  while ((tq + 1) * (tq + 2) / 2 <= ti) ++tq;
  while (tq * (tq + 1) / 2 > ti) --tq;
  int ts = ti - tq * (tq + 1) / 2;
  int tid = threadIdx.x;
  int w = tid >> 6, lane = tid & 63;
  int g = lane >> 4, c = lane & 15;
  int m0 = (w >> 1) * 64, n0 = (w & 1) * 64;
  const ushort_t* Ah = Qhi + (size_t)bh * T_DIM * D_DIM + (size_t)(tq * 128) * D_DIM;
  const ushort_t* Al = Qlo + (size_t)bh * T_DIM * D_DIM + (size_t)(tq * 128) * D_DIM;
  const ushort_t* Bh = Khi + (size_t)b * T_DIM * D_DIM + (size_t)(ts * 128) * D_DIM;
  const ushort_t* Bl = Klo + (size_t)b * T_DIM * D_DIM + (size_t)(ts * 128) * D_DIM;
  f32x4 zero4 = {0.f, 0.f, 0.f, 0.f};
  f32x4 acc[4][4];
#pragma unroll
  for (int ii = 0; ii < 4; ++ii)
#pragma unroll
    for (int jj = 0; jj < 4; ++jj) acc[ii][jj] = zero4;
  for (int kc = 0; kc < 16; ++kc) {
    int k0 = kc * 32;
    stage128x32(Ah + k0, D_DIM, lAh, tid);
    stage128x32(Al + k0, D_DIM, lAl, tid);
    stage128x32(Bh + k0, D_DIM, lBh, tid);
    stage128x32(Bl + k0, D_DIM, lBl, tid);
    __syncthreads();
    bf16x8 ah[4], al[4], bh8[4], bl8[4];
#pragma unroll
    for (int mf = 0; mf < 4; ++mf) {
      int ro = (m0 + 16 * mf + c) * 32 + g * 8;
      ah[mf] = *(const bf16x8*)&lAh[ro];
      al[mf] = *(const bf16x8*)&lAl[ro];
    }
#pragma unroll
    for (int nf = 0; nf < 4; ++nf) {
      int ro = (n0 + 16 * nf + c) * 32 + g * 8;
      bh8[nf] = *(const bf16x8*)&lBh[ro];
      bl8[nf] = *(const bf16x8*)&lBl[ro];
    }
#pragma unroll
    for (int mf = 0; mf < 4; ++mf)
#pragma unroll
      for (int nf = 0; nf < 4; ++nf) {
        acc[mf][nf] = mfma16(ah[mf], bh8[nf], acc[mf][nf]);
        acc[mf][nf] = mfma16(ah[mf], bl8[nf], acc[mf][nf]);
        acc[mf][nf] = mfma16(al[mf], bh8[nf], acc[mf][nf]);
      }
    __syncthreads();
  }
  size_t slot = (size_t)(bhl * 136 + tq * (tq + 1) / 2 + ts);
  float* Sslot = S + slot * SLOT_F;
#pragma unroll
  for (int mf = 0; mf < 4; ++mf)
#pragma unroll
    for (int nf = 0; nf < 4; ++nf)
#pragma unroll
      for (int i2 = 0; i2 < 4; ++i2) {
        int lq = m0 + 16 * mf + 4 * g + i2;
        int ls = n0 + 16 * nf + c;
        Sslot[(size_t)lq * 128 + ls] = acc[mf][nf][i2];
      }
  // ---- stats epilogue (safe: all waves past final K-loop barrier; LDS reusable) ----
  float* smax = (float*)lAh;          // [2][128]
  float* ssum = (float*)lAl;          // [2][128]
  float* mfin = (float*)lBh;          // [128]
  int diag = (ts == tq);
  float rm[16];
#pragma unroll
  for (int mf = 0; mf < 4; ++mf)
#pragma unroll
    for (int i2 = 0; i2 < 4; ++i2) {
      int idx = mf * 4 + i2;
      int row_l = m0 + 16 * mf + 4 * g + i2;
      float v = -3.0e38f;
#pragma unroll
      for (int nf = 0; nf < 4; ++nf) {
        int col_l = n0 + 16 * nf + c;
        if (!diag || col_l <= row_l) v = fmaxf(v, acc[mf][nf][i2]);
      }
      rm[idx] = v;
    }
#pragma unroll
  for (int off = 1; off < 16; off <<= 1)
#pragma unroll
    for (int idx = 0; idx < 16; ++idx) rm[idx] = fmaxf(rm[idx], __shfl_xor(rm[idx], off));
  if (c == 0) {
#pragma unroll
    for (int mf = 0; mf < 4; ++mf)
#pragma unroll
      for (int i2 = 0; i2 < 4; ++i2)
        smax[(w & 1) * 128 + m0 + 16 * mf + 4 * g + i2] = rm[mf * 4 + i2];
  }
  __syncthreads();
  if (tid < 128) mfin[tid] = fmaxf(smax[tid], smax[128 + tid]);
  __syncthreads();
  float rs[16];
#pragma unroll
  for (int mf = 0; mf < 4; ++mf)
#pragma unroll
    for (int i2 = 0; i2 < 4; ++i2) {
      int idx = mf * 4 + i2;
      int row_l = m0 + 16 * mf + 4 * g + i2;
      float mrow = mfin[row_l];
      float s_ = 0.f;
#pragma unroll
      for (int nf = 0; nf < 4; ++nf) {
        int col_l = n0 + 16 * nf + c;
        if (!diag || col_l <= row_l) s_ += __expf(acc[mf][nf][i2] - mrow);
      }
      rs[idx] = s_;
    }
#pragma unroll
  for (int off = 1; off < 16; off <<= 1)
#pragma unroll
    for (int idx = 0; idx < 16; ++idx) rs[idx] += __shfl_xor(rs[idx], off);
  if (c == 0) {
#pragma unroll
    for (int mf = 0; mf < 4; ++mf)
#pragma unroll
      for (int i2 = 0; i2 < 4; ++i2)
        ssum[(w & 1) * 128 + m0 + 16 * mf + 4 * g + i2] = rs[mf * 4 + i2];
  }
  __syncthreads();
  if (tid < 128) {
    statm[slot * 128 + tid] = mfin[tid];
    statl[slot * 128 + tid] = ssum[tid] + ssum[128 + tid];
  }
}

// ---------------- combine per-tile stats -> per-row (m, 1/l) ----------------------
__global__ __launch_bounds__(128) void combine_kernel(const float* __restrict__ statm,
    const float* __restrict__ statl, float2* __restrict__ mst, int nbc) {
  int mlanes = nbc * 8;
  int bid = blockIdx.x;               // mlanes * 16
  int bhl = bid % mlanes;
  int tq = bid / mlanes;
  int r = threadIdx.x;
  size_t base = (size_t)(bhl * 136 + tq * (tq + 1) / 2);
  float m = -3.0e38f;
  for (int t = 0; t <= tq; ++t) m = fmaxf(m, statm[(base + t) * 128 + r]);
  float l = 0.f;
  for (int t = 0; t <= tq; ++t)
    l += __expf(statm[(base + t) * 128 + r] - m) * statl[(base + t) * 128 + r];
  mst[((size_t)(bhl * 16 + tq)) * 128 + r] = make_float2(m, 1.0f / l);
}

// ---------------- PV-GEMM: out = softmax(S) @ h, exp fused into A staging ----------
// A: reg-staged from fp32 S with p = f2bf(exp(s-m)*inv_l) (identical rounding to the
// old softmax kernel); diagonal tile masked to 0. B: global_load_lds as before.
__global__ __launch_bounds__(256, 2) void pv_kernel(const float* __restrict__ Sf,
    const float2* __restrict__ mst, const ushort_t* __restrict__ hT,
    float* __restrict__ out, int b0, int nbc) {
  __shared__ ushort_t lA[128 * 32], lB[128 * 32];
  __shared__ float2 ml[128];
  int mlanes = nbc * 8;
  int i = blockIdx.x;                 // (nbc*8) bh (fastest) x tqi(16, heavy first) x nt(4)
  int j = i % mlanes;
  int rem = i / mlanes;
  int nt = rem & 3;
  int tq = 15 - (rem >> 2);           // heavy tiles first
  int bl, hd;
  decode_bh(j, nbc, bl, hd);
  int b = b0 + bl;
  int bhl = bl * NH + hd;
  int tid = threadIdx.x;
  int w = tid >> 6, lane = tid & 63;
  int g = lane >> 4, c = lane & 15;
  int m0 = (w >> 1) * 64, n0 = (w & 1) * 64;
  size_t pslot = (size_t)(bhl * 136 + tq * (tq + 1) / 2);
  const ushort_t* Bb = hT + (size_t)b * D_DIM * T_DIM + (size_t)(nt * 128) * T_DIM;
  // prologue: per-row (m, 1/l)
  for (int r = tid; r < 128; r += 256) ml[r] = mst[((size_t)(bhl * 16 + tq)) * 128 + r];
  __syncthreads();
  f32x4 zero4 = {0.f, 0.f, 0.f, 0.f};
  f32x4 acc[4][4];
#pragma unroll
  for (int ii = 0; ii < 4; ++ii)
#pragma unroll
    for (int jj = 0; jj < 4; ++jj) acc[ii][jj] = zero4;
  int nk = (tq + 1) * 4;
  for (int kc = 0; kc < nk; ++kc) {
    int ti_ = kc >> 2;
    int diag = (ti_ == tq);
    int w0 = (kc & 3) << 5;           // 32-col window base within tile
    const float* Af = Sf + (pslot + ti_) * SLOT_F + w0;
#pragma unroll
    for (int p = 0; p < 2; ++p) {
      int tt = p * 256 + tid;
      int r = tt >> 2, cb = (tt & 3) << 3;
      const float* src = Af + (size_t)r * 128 + cb;
      float4 v0 = *(const float4*)src;
      float4 v1 = *(const float4*)(src + 4);
      float2 s_ = ml[r];
      int lim = diag ? (r - w0 - cb) : 7;   // cols j<=lim valid (col<=row)
      float e[8] = {v0.x, v0.y, v0.z, v0.w, v1.x, v1.y, v1.z, v1.w};
      union { bf16x8 v8; ushort_t u[8]; } pk;
#pragma unroll
      for (int jj = 0; jj < 8; ++jj) {
        float ev = __expf(e[jj] - s_.x) * s_.y;
        pk.u[jj] = (jj <= lim) ? f2bf(ev) : (ushort_t)0;
      }
      *(bf16x8*)&lA[r * 32 + cb] = pk.v8;
    }
    stage128x32(Bb + kc * 32, T_DIM, lB, tid);
    __syncthreads();
    bf16x8 af[4], bf[4];
#pragma unroll
    for (int mf = 0; mf < 4; ++mf)
      af[mf] = *(const bf16x8*)&lA[(m0 + 16 * mf + c) * 32 + g * 8];
#pragma unroll
    for (int nf = 0; nf < 4; ++nf)
      bf[nf] = *(const bf16x8*)&lB[(n0 + 16 * nf + c) * 32 + g * 8];
#pragma unroll
    for (int mf = 0; mf < 4; ++mf)
#pragma unroll
      for (int nf = 0; nf < 4; ++nf) acc[mf][nf] = mfma16(af[mf], bf[nf], acc[mf][nf]);
    __syncthreads();
  }
  size_t obase = (size_t)((b * NH + hd)) * T_DIM * D_DIM;
#pragma unroll
  for (int mf = 0; mf < 4; ++mf)
#pragma unroll
    for (int nf = 0; nf < 4; ++nf)
#pragma unroll
      for (int i2 = 0; i2 < 4; ++i2) {
        int q = tq * 128 + m0 + 16 * mf + 4 * g + i2;
        int d = nt * 128 + n0 + 16 * nf + c;
        out[obase + (size_t)q * D_DIM + d] = acc[mf][nf][i2];
      }
}

extern "C" void kernel_launch(void* const* d_in, const int* in_sizes, int n_in,
                              void* d_out, int out_size, void* d_ws, size_t ws_size,
                              hipStream_t stream) {
  const float* h = (const float*)d_in[0];
  const float* A = (const float*)d_in[1];
  float* out = (float*)d_out;
  char* ws = (char*)d_ws;
  const size_t SZ_H = (size_t)NB * T_DIM * D_DIM * sizeof(ushort_t);      // 4 MB
  const size_t SZ_A = (size_t)NH * D_DIM * D_DIM * sizeof(ushort_t);      // 4 MB
  const size_t SZ_Q = (size_t)NB * NH * T_DIM * D_DIM * sizeof(ushort_t); // 33.5 MB
  const size_t SZ_SB = 136ull * SLOT_F * sizeof(float) * NH;              // 71.3 MB/batch
  const size_t FIXED = 3 * SZ_H + 2 * SZ_A + 2 * SZ_Q;                    // 87.2 MB
  ushort_t* hhi  = (ushort_t*)(ws);
  ushort_t* hlo  = (ushort_t*)(ws + SZ_H);
  ushort_t* hT   = (ushort_t*)(ws + 2 * SZ_H);
  ushort_t* AThi = (ushort_t*)(ws + 3 * SZ_H);
  ushort_t* ATlo = (ushort_t*)(ws + 3 * SZ_H + SZ_A);
  ushort_t* Qhi  = (ushort_t*)(ws + 3 * SZ_H + 2 * SZ_A);
  ushort_t* Qlo  = (ushort_t*)(ws + 3 * SZ_H + 2 * SZ_A + SZ_Q);
  float*    Sbuf = (float*)   (ws + FIXED);

  // stats sizes depend on nbc; pick largest nbc whose footprint fits
  int nbc = 2;
  for (;;) {
    size_t stat1 = (size_t)nbc * 8 * 136 * 128 * sizeof(float);   // statm (and statl)
    size_t mstsz = (size_t)nbc * 8 * 16 * 128 * sizeof(float2);
    if (FIXED + (size_t)nbc * SZ_SB + 2 * stat1 + mstsz <= ws_size || nbc == 1) break;
    nbc = 1;
  }
  size_t stat1 = (size_t)nbc * 8 * 136 * 128 * sizeof(float);
  float*  statm = (float*)(ws + FIXED + (size_t)nbc * SZ_SB);
  float*  statl = (float*)(ws + FIXED + (size_t)nbc * SZ_SB + stat1);
  float2* mst   = (float2*)(ws + FIXED + (size_t)nbc * SZ_SB + 2 * stat1);

  split_h_kernel<<<512, 256, 0, stream>>>(h, hhi, hlo, hT);
  split_AT_kernel<<<512, 256, 0, stream>>>(A, AThi, ATlo);
  qgemm_kernel<<<1024, 256, 0, stream>>>(hhi, hlo, AThi, ATlo, Qhi, Qlo);
  for (int b0 = 0; b0 < NB; b0 += nbc) {
    sgemm_kernel<<<nbc * 8 * 136, 256, 0, stream>>>(Qhi, Qlo, hhi, hlo, Sbuf,
                                                    statm, statl, b0, nbc);
    combine_kernel<<<nbc * 8 * 16, 128, 0, stream>>>(statm, statl, mst, nbc);
    pv_kernel<<<nbc * 512, 256, 0, stream>>>(Sbuf, mst, hT, out, b0, nbc);
  }
}

// Round 11
// 345.261 us; speedup vs baseline: 1.2457x; 1.2457x over previous
//
#include <hip/hip_runtime.h>

typedef unsigned short ushort_t;
typedef __attribute__((ext_vector_type(8))) short bf16x8;
typedef __attribute__((ext_vector_type(4))) float f32x4;
typedef __attribute__((ext_vector_type(4))) unsigned short u16x4;

#define T_DIM 2048
#define D_DIM 512
#define NH 8
#define NB 2
// S is stored tile-packed: per (batch,head), 136 causal tiles of 128x128 fp32
// (64KB slots). Slot index for tile (tq,ts) = tq*(tq+1)/2 + ts. P (bf16) is
// written in place over each slot (row stride 256 ushorts, 128 used).
#define SLOT_F 16384          // fp32 elems per slot (128*128)
#define SLOT_U 32768          // ushort elems per slot

static __device__ __forceinline__ ushort_t f2bf(float x) {
  union { float f; unsigned u; } v; v.f = x;
  unsigned r = v.u + 0x7fffu + ((v.u >> 16) & 1u);
  return (ushort_t)(r >> 16);
}
static __device__ __forceinline__ float bf2f(ushort_t b) {
  union { unsigned u; float f; } v; v.u = ((unsigned)b) << 16;
  return v.f;
}
static __device__ __forceinline__ f32x4 mfma16(bf16x8 a, bf16x8 b, f32x4 c) {
  return __builtin_amdgcn_mfma_f32_16x16x32_bf16(a, b, c, 0, 0, 0);
}

typedef const __attribute__((address_space(1))) unsigned asg_t;
typedef __attribute__((address_space(3))) unsigned asl_t;
static __device__ __forceinline__ void gload16(const ushort_t* g, ushort_t* l) {
  __builtin_amdgcn_global_load_lds((asg_t*)g, (asl_t*)l, 16, 0, 0);
}

// stage a [128][32] bf16 tile (8KB) from global rows (stride ldk) into LDS.
// dest: wave-uniform base + lane*16B (HW rule); per-lane global source addresses.
static __device__ __forceinline__ void stage128x32(const ushort_t* __restrict__ src,
                                                   size_t ldk, ushort_t* lds, int tid) {
  int w = tid >> 6;
#pragma unroll
  for (int p = 0; p < 2; ++p) {
    int t = p * 256 + tid;          // 512 chunks of 8 elems
    int r = t >> 2;                 // row 0..127
    int col = (t & 3) << 3;         // 0,8,16,24
    gload16(src + (size_t)r * ldk + col, lds + p * 2048 + (w << 9));
  }
}

// decode fastest grid index j (0..8*nbc-1) -> (bl, hd): head<->XCD affinity.
static __device__ __forceinline__ void decode_bh(int j, int nbc, int& bl, int& hd) {
  if (nbc == 2) { bl = j & 1; hd = j >> 1; } else { bl = 0; hd = j; }
}

// ---------------- split h -> h_hi/h_lo (bf16) + hT (bf16 transpose) ----------------
__global__ __launch_bounds__(256) void split_h_kernel(const float* __restrict__ h,
    ushort_t* __restrict__ hhi, ushort_t* __restrict__ hlo, ushort_t* __restrict__ hT) {
  __shared__ ushort_t lds[64][68];
  int x = blockIdx.x;                 // 512 = b(2) x tt(32) x ee(8)
  int b = x >> 8, tt = (x >> 3) & 31, ee = x & 7;
  int t0 = tt * 64, e0 = ee * 64;
  int rr = threadIdx.x >> 4;
  int c4 = (threadIdx.x & 15) * 4;
#pragma unroll
  for (int it = 0; it < 4; ++it) {
    int t = it * 16 + rr;
    size_t idx = ((size_t)(b * T_DIM + t0 + t)) * D_DIM + e0 + c4;
    float4 v = *(const float4*)(h + idx);
    u16x4 hv, lv;
    hv[0] = f2bf(v.x); lv[0] = f2bf(v.x - bf2f(hv[0]));
    hv[1] = f2bf(v.y); lv[1] = f2bf(v.y - bf2f(hv[1]));
    hv[2] = f2bf(v.z); lv[2] = f2bf(v.z - bf2f(hv[2]));
    hv[3] = f2bf(v.w); lv[3] = f2bf(v.w - bf2f(hv[3]));
    *(u16x4*)(hhi + idx) = hv;
    *(u16x4*)(hlo + idx) = lv;
    *(u16x4*)&lds[t][c4] = hv;
  }
  __syncthreads();
#pragma unroll
  for (int it = 0; it < 4; ++it) {
    int e = it * 16 + rr;
    u16x4 wv;
    wv[0] = lds[c4 + 0][e];
    wv[1] = lds[c4 + 1][e];
    wv[2] = lds[c4 + 2][e];
    wv[3] = lds[c4 + 3][e];
    *(u16x4*)(hT + ((size_t)(b * D_DIM + e0 + e)) * T_DIM + t0 + c4) = wv;
  }
}

// ---------------- split+transpose A -> AT_hi/AT_lo ([head][e][d], d contiguous) ----
__global__ __launch_bounds__(256) void split_AT_kernel(const float* __restrict__ A,
    ushort_t* __restrict__ AThi, ushort_t* __restrict__ ATlo) {
  __shared__ ushort_t ldh[64][68];
  __shared__ ushort_t ldl[64][68];
  int x = blockIdx.x;                 // 512 = head(8) x dd(8) x ee(8)
  int hd = x >> 6, dd = (x >> 3) & 7, ee = x & 7;
  int d0 = dd * 64, e0 = ee * 64;
  int rr = threadIdx.x >> 4;
  int c4 = (threadIdx.x & 15) * 4;
#pragma unroll
  for (int it = 0; it < 4; ++it) {
    int d = it * 16 + rr;
    float4 v = *(const float4*)(A + ((size_t)(hd * D_DIM + d0 + d)) * D_DIM + e0 + c4);
    u16x4 hv, lv;
    hv[0] = f2bf(v.x); lv[0] = f2bf(v.x - bf2f(hv[0]));
    hv[1] = f2bf(v.y); lv[1] = f2bf(v.y - bf2f(hv[1]));
    hv[2] = f2bf(v.z); lv[2] = f2bf(v.z - bf2f(hv[2]));
    hv[3] = f2bf(v.w); lv[3] = f2bf(v.w - bf2f(hv[3]));
    *(u16x4*)&ldh[d][c4] = hv;
    *(u16x4*)&ldl[d][c4] = lv;
  }
  __syncthreads();
#pragma unroll
  for (int it = 0; it < 4; ++it) {
    int e = it * 16 + rr;
    u16x4 wh, wl;
    wh[0] = ldh[c4 + 0][e]; wl[0] = ldl[c4 + 0][e];
    wh[1] = ldh[c4 + 1][e]; wl[1] = ldl[c4 + 1][e];
    wh[2] = ldh[c4 + 2][e]; wl[2] = ldl[c4 + 2][e];
    wh[3] = ldh[c4 + 3][e]; wl[3] = ldl[c4 + 3][e];
    size_t o = ((size_t)(hd * D_DIM + e0 + e)) * D_DIM + d0 + c4;
    *(u16x4*)(AThi + o) = wh;
    *(u16x4*)(ATlo + o) = wl;
  }
}

// ---------------- Q-GEMM: Q[b,hd] = h_b @ A_hd (split x3), 3-group MFMA ------------
// Grouped loads cut peak live fragments 64->48 regs; per-acc-element order is
// unchanged (hh, then ah*bl, then al*bh) -> bit-identical accumulation.
// launch_bounds(256,4): cap 128 total regs -> 4 waves/SIMD occupancy bucket.
__global__ __launch_bounds__(256, 4) void qgemm_kernel(
    const ushort_t* __restrict__ hhi, const ushort_t* __restrict__ hlo,
    const ushort_t* __restrict__ AThi, const ushort_t* __restrict__ ATlo,
    ushort_t* __restrict__ Qhi, ushort_t* __restrict__ Qlo) {
  __shared__ ushort_t lAh[128 * 32], lAl[128 * 32], lBh[128 * 32], lBl[128 * 32];
  int bid = blockIdx.x;               // 1024 = mt(16) x nt(4) x b(2) x hd(8), hd fastest
  int hd = bid & 7;
  int rem = bid >> 3;
  int nt = rem & 3;
  int mt = (rem >> 2) & 15;
  int b = rem >> 6;
  int bh = b * NH + hd;
  int tid = threadIdx.x;
  int w = tid >> 6, lane = tid & 63;
  int g = lane >> 4, c = lane & 15;
  int m0 = (w >> 1) * 64, n0 = (w & 1) * 64;
  const ushort_t* Ah = hhi + (size_t)b * T_DIM * D_DIM + (size_t)(mt * 128) * D_DIM;
  const ushort_t* Al = hlo + (size_t)b * T_DIM * D_DIM + (size_t)(mt * 128) * D_DIM;
  const ushort_t* Bh = AThi + (size_t)hd * D_DIM * D_DIM + (size_t)(nt * 128) * D_DIM;
  const ushort_t* Bl = ATlo + (size_t)hd * D_DIM * D_DIM + (size_t)(nt * 128) * D_DIM;
  f32x4 zero4 = {0.f, 0.f, 0.f, 0.f};
  f32x4 acc[4][4];
#pragma unroll
  for (int i = 0; i < 4; ++i)
#pragma unroll
    for (int j = 0; j < 4; ++j) acc[i][j] = zero4;
  for (int kc = 0; kc < 16; ++kc) {
    int k0 = kc * 32;
    stage128x32(Ah + k0, D_DIM, lAh, tid);
    stage128x32(Al + k0, D_DIM, lAl, tid);
    stage128x32(Bh + k0, D_DIM, lBh, tid);
    stage128x32(Bl + k0, D_DIM, lBl, tid);
    __syncthreads();
    {
      bf16x8 ah[4], bh8[4];
#pragma unroll
      for (int mf = 0; mf < 4; ++mf) ah[mf] = *(const bf16x8*)&lAh[(m0 + 16 * mf + c) * 32 + g * 8];
#pragma unroll
      for (int nf = 0; nf < 4; ++nf) bh8[nf] = *(const bf16x8*)&lBh[(n0 + 16 * nf + c) * 32 + g * 8];
#pragma unroll
      for (int mf = 0; mf < 4; ++mf)
#pragma unroll
        for (int nf = 0; nf < 4; ++nf) acc[mf][nf] = mfma16(ah[mf], bh8[nf], acc[mf][nf]);
      bf16x8 bl8[4];
#pragma unroll
      for (int nf = 0; nf < 4; ++nf) bl8[nf] = *(const bf16x8*)&lBl[(n0 + 16 * nf + c) * 32 + g * 8];
#pragma unroll
      for (int mf = 0; mf < 4; ++mf)
#pragma unroll
        for (int nf = 0; nf < 4; ++nf) acc[mf][nf] = mfma16(ah[mf], bl8[nf], acc[mf][nf]);
      bf16x8 al[4];
#pragma unroll
      for (int mf = 0; mf < 4; ++mf) al[mf] = *(const bf16x8*)&lAl[(m0 + 16 * mf + c) * 32 + g * 8];
#pragma unroll
      for (int mf = 0; mf < 4; ++mf)
#pragma unroll
        for (int nf = 0; nf < 4; ++nf) acc[mf][nf] = mfma16(al[mf], bh8[nf], acc[mf][nf]);
    }
    __syncthreads();
  }
  size_t qbase = (size_t)bh * T_DIM * D_DIM;
#pragma unroll
  for (int mf = 0; mf < 4; ++mf)
#pragma unroll
    for (int nf = 0; nf < 4; ++nf)
#pragma unroll
      for (int i2 = 0; i2 < 4; ++i2) {
        int q = mt * 128 + m0 + 16 * mf + 4 * g + i2;
        int e = nt * 128 + n0 + 16 * nf + c;
        float v = acc[mf][nf][i2];
        ushort_t hi = f2bf(v);
        ushort_t lo = f2bf(v - bf2f(hi));
        Qhi[qbase + (size_t)q * D_DIM + e] = hi;
        Qlo[qbase + (size_t)q * D_DIM + e] = lo;
      }
}

// ---------------- S-GEMM: causal lower-tri tiles, S = Q @ K^T (split x3) ----------
// Writes into tile-packed S slots. Covers nbc batches in one dispatch.
// Same 3-group MFMA restructure + launch_bounds(256,4) as qgemm.
__global__ __launch_bounds__(256, 4) void sgemm_kernel(
    const ushort_t* __restrict__ Qhi, const ushort_t* __restrict__ Qlo,
    const ushort_t* __restrict__ Khi, const ushort_t* __restrict__ Klo,
    float* __restrict__ S, int b0, int nbc) {
  __shared__ ushort_t lAh[128 * 32], lAl[128 * 32], lBh[128 * 32], lBl[128 * 32];
  int mlanes = nbc * 8;
  int i = blockIdx.x;                 // (nbc*8) bh (fastest) x 136 lower-tri tiles
  int j = i % mlanes, ti = i / mlanes;
  int bl, hd;
  decode_bh(j, nbc, bl, hd);
  int b = b0 + bl;
  int bh = b * NH + hd;
  int bhl = bl * NH + hd;
  int tq = (int)((sqrtf(8.f * (float)ti + 1.f) - 1.f) * 0.5f);
  while ((tq + 1) * (tq + 2) / 2 <= ti) ++tq;
  while (tq * (tq + 1) / 2 > ti) --tq;
  int ts = ti - tq * (tq + 1) / 2;
  int tid = threadIdx.x;
  int w = tid >> 6, lane = tid & 63;
  int g = lane >> 4, c = lane & 15;
  int m0 = (w >> 1) * 64, n0 = (w & 1) * 64;
  const ushort_t* Ah = Qhi + (size_t)bh * T_DIM * D_DIM + (size_t)(tq * 128) * D_DIM;
  const ushort_t* Al = Qlo + (size_t)bh * T_DIM * D_DIM + (size_t)(tq * 128) * D_DIM;
  const ushort_t* Bh = Khi + (size_t)b * T_DIM * D_DIM + (size_t)(ts * 128) * D_DIM;
  const ushort_t* Bl = Klo + (size_t)b * T_DIM * D_DIM + (size_t)(ts * 128) * D_DIM;
  f32x4 zero4 = {0.f, 0.f, 0.f, 0.f};
  f32x4 acc[4][4];
#pragma unroll
  for (int ii = 0; ii < 4; ++ii)
#pragma unroll
    for (int jj = 0; jj < 4; ++jj) acc[ii][jj] = zero4;
  for (int kc = 0; kc < 16; ++kc) {
    int k0 = kc * 32;
    stage128x32(Ah + k0, D_DIM, lAh, tid);
    stage128x32(Al + k0, D_DIM, lAl, tid);
    stage128x32(Bh + k0, D_DIM, lBh, tid);
    stage128x32(Bl + k0, D_DIM, lBl, tid);
    __syncthreads();
    {
      bf16x8 ah[4], bh8[4];
#pragma unroll
      for (int mf = 0; mf < 4; ++mf) ah[mf] = *(const bf16x8*)&lAh[(m0 + 16 * mf + c) * 32 + g * 8];
#pragma unroll
      for (int nf = 0; nf < 4; ++nf) bh8[nf] = *(const bf16x8*)&lBh[(n0 + 16 * nf + c) * 32 + g * 8];
#pragma unroll
      for (int mf = 0; mf < 4; ++mf)
#pragma unroll
        for (int nf = 0; nf < 4; ++nf) acc[mf][nf] = mfma16(ah[mf], bh8[nf], acc[mf][nf]);
      bf16x8 bl8[4];
#pragma unroll
      for (int nf = 0; nf < 4; ++nf) bl8[nf] = *(const bf16x8*)&lBl[(n0 + 16 * nf + c) * 32 + g * 8];
#pragma unroll
      for (int mf = 0; mf < 4; ++mf)
#pragma unroll
        for (int nf = 0; nf < 4; ++nf) acc[mf][nf] = mfma16(ah[mf], bl8[nf], acc[mf][nf]);
      bf16x8 al[4];
#pragma unroll
      for (int mf = 0; mf < 4; ++mf) al[mf] = *(const bf16x8*)&lAl[(m0 + 16 * mf + c) * 32 + g * 8];
#pragma unroll
      for (int mf = 0; mf < 4; ++mf)
#pragma unroll
        for (int nf = 0; nf < 4; ++nf) acc[mf][nf] = mfma16(al[mf], bh8[nf], acc[mf][nf]);
    }
    __syncthreads();
  }
  float* Sslot = S + ((size_t)(bhl * 136 + tq * (tq + 1) / 2 + ts)) * SLOT_F;
#pragma unroll
  for (int mf = 0; mf < 4; ++mf)
#pragma unroll
    for (int nf = 0; nf < 4; ++nf)
#pragma unroll
      for (int i2 = 0; i2 < 4; ++i2) {
        int lq = m0 + 16 * mf + 4 * g + i2;   // local row in tile
        int ls = n0 + 16 * nf + c;            // local col in tile
        Sslot[(size_t)lq * 128 + ls] = acc[mf][nf][i2];
      }
}

// ------- row softmax over tile-packed S: fp32 -> P bf16 IN PLACE, zero-padded ------
// Safe aliasing: all fp32-row reads happen before the first __syncthreads; the bf16
// overwrite of the same row happens only after the last one.
__global__ __launch_bounds__(256) void softmax_kernel(float* __restrict__ S, int nbc) {
  __shared__ float rowbuf[2048];
  __shared__ float red[4];
  int mlanes = nbc * 8;
  int i = blockIdx.x;                 // (nbc*8) bh (fastest) x 2048 rows
  int j = i % mlanes, q = i / mlanes;
  int bl, hd;
  decode_bh(j, nbc, bl, hd);
  int bhl = bl * NH + hd;
  int tq = q >> 7, lq = q & 127;
  float* Sb = S + (size_t)bhl * 136 * SLOT_F;
  size_t rowf = (size_t)(tq * (tq + 1) / 2) * SLOT_F + (size_t)lq * 128;
  int n = q + 1;
  int nout = (tq + 1) << 7;
  int tid = threadIdx.x;
  float mx = -3.0e38f;
  for (int s0 = tid * 4; s0 < nout; s0 += 1024) {
    int ts = s0 >> 7;
    const float* src = Sb + rowf + (size_t)ts * SLOT_F + (s0 & 127);
    float4 v = make_float4(-3.0e38f, -3.0e38f, -3.0e38f, -3.0e38f);
    if (s0 < n) v = *(const float4*)src;
    float a0 = (s0 + 0 < n) ? v.x : -3.0e38f;
    float a1 = (s0 + 1 < n) ? v.y : -3.0e38f;
    float a2 = (s0 + 2 < n) ? v.z : -3.0e38f;
    float a3 = (s0 + 3 < n) ? v.w : -3.0e38f;
    rowbuf[s0 + 0] = a0; rowbuf[s0 + 1] = a1;
    rowbuf[s0 + 2] = a2; rowbuf[s0 + 3] = a3;
    mx = fmaxf(mx, fmaxf(fmaxf(a0, a1), fmaxf(a2, a3)));
  }
#pragma unroll
  for (int off = 1; off < 64; off <<= 1) mx = fmaxf(mx, __shfl_xor(mx, off));
  if ((tid & 63) == 0) red[tid >> 6] = mx;
  __syncthreads();
  mx = fmaxf(fmaxf(red[0], red[1]), fmaxf(red[2], red[3]));
  float sum = 0.f;
  for (int s0 = tid * 4; s0 < nout; s0 += 1024) {
    float e0 = __expf(rowbuf[s0 + 0] - mx);
    float e1 = __expf(rowbuf[s0 + 1] - mx);
    float e2 = __expf(rowbuf[s0 + 2] - mx);
    float e3 = __expf(rowbuf[s0 + 3] - mx);
    rowbuf[s0 + 0] = e0; rowbuf[s0 + 1] = e1;
    rowbuf[s0 + 2] = e2; rowbuf[s0 + 3] = e3;
    sum += (e0 + e1) + (e2 + e3);
  }
#pragma unroll
  for (int off = 1; off < 64; off <<= 1) sum += __shfl_xor(sum, off);
  __syncthreads();
  if ((tid & 63) == 0) red[tid >> 6] = sum;
  __syncthreads();
  float inv = 1.0f / ((red[0] + red[1]) + (red[2] + red[3]));
  for (int s0 = tid * 4; s0 < nout; s0 += 1024) {
    int ts = s0 >> 7;
    ushort_t* dst = (ushort_t*)Sb + 2 * (rowf + (size_t)ts * SLOT_F) + (s0 & 127);
    u16x4 o;
    o[0] = f2bf(rowbuf[s0 + 0] * inv);
    o[1] = f2bf(rowbuf[s0 + 1] * inv);
    o[2] = f2bf(rowbuf[s0 + 2] * inv);
    o[3] = f2bf(rowbuf[s0 + 3] * inv);
    *(u16x4*)dst = o;
  }
}

// ---------------- PV-GEMM: out = P @ h (causal K range), plain bf16 ----------------
// A-operand read from tile-packed P (bf16 in place over S slots, row stride 256).
// 124 total regs -> launch_bounds(256,4) unlocks the 4-waves/SIMD bucket.
__global__ __launch_bounds__(256, 4) void pv_kernel(const ushort_t* __restrict__ P,
    const ushort_t* __restrict__ hT, float* __restrict__ out, int b0, int nbc) {
  __shared__ ushort_t lA[128 * 32], lB[128 * 32];
  int mlanes = nbc * 8;
  int i = blockIdx.x;                 // (nbc*8) bh (fastest) x tqi(16, heavy first) x nt(4)
  int j = i % mlanes;
  int rem = i / mlanes;
  int nt = rem & 3;
  int tq = 15 - (rem >> 2);           // heavy tiles first
  int bl, hd;
  decode_bh(j, nbc, bl, hd);
  int b = b0 + bl;
  int bhl = bl * NH + hd;
  int tid = threadIdx.x;
  int w = tid >> 6, lane = tid & 63;
  int g = lane >> 4, c = lane & 15;
  int m0 = (w >> 1) * 64, n0 = (w & 1) * 64;
  size_t pslot = (size_t)(bhl * 136 + tq * (tq + 1) / 2);
  const ushort_t* Bb = hT + (size_t)b * D_DIM * T_DIM + (size_t)(nt * 128) * T_DIM;
  f32x4 zero4 = {0.f, 0.f, 0.f, 0.f};
  f32x4 acc[4][4];
#pragma unroll
  for (int ii = 0; ii < 4; ++ii)
#pragma unroll
    for (int jj = 0; jj < 4; ++jj) acc[ii][jj] = zero4;
  int nk = (tq + 1) * 4;
  for (int kc = 0; kc < nk; ++kc) {
    const ushort_t* Asrc = P + (pslot + (kc >> 2)) * SLOT_U + ((kc & 3) << 5);
    stage128x32(Asrc, 256, lA, tid);
    stage128x32(Bb + kc * 32, T_DIM, lB, tid);
    __syncthreads();
    bf16x8 af[4], bf[4];
#pragma unroll
    for (int mf = 0; mf < 4; ++mf)
      af[mf] = *(const bf16x8*)&lA[(m0 + 16 * mf + c) * 32 + g * 8];
#pragma unroll
    for (int nf = 0; nf < 4; ++nf)
      bf[nf] = *(const bf16x8*)&lB[(n0 + 16 * nf + c) * 32 + g * 8];
#pragma unroll
    for (int mf = 0; mf < 4; ++mf)
#pragma unroll
      for (int nf = 0; nf < 4; ++nf) acc[mf][nf] = mfma16(af[mf], bf[nf], acc[mf][nf]);
    __syncthreads();
  }
  size_t obase = (size_t)((b * NH + hd)) * T_DIM * D_DIM;
#pragma unroll
  for (int mf = 0; mf < 4; ++mf)
#pragma unroll
    for (int nf = 0; nf < 4; ++nf)
#pragma unroll
      for (int i2 = 0; i2 < 4; ++i2) {
        int q = tq * 128 + m0 + 16 * mf + 4 * g + i2;
        int d = nt * 128 + n0 + 16 * nf + c;
        out[obase + (size_t)q * D_DIM + d] = acc[mf][nf][i2];
      }
}

extern "C" void kernel_launch(void* const* d_in, const int* in_sizes, int n_in,
                              void* d_out, int out_size, void* d_ws, size_t ws_size,
                              hipStream_t stream) {
  const float* h = (const float*)d_in[0];
  const float* A = (const float*)d_in[1];
  float* out = (float*)d_out;
  char* ws = (char*)d_ws;
  const size_t SZ_H = (size_t)NB * T_DIM * D_DIM * sizeof(ushort_t);      // 4 MB
  const size_t SZ_A = (size_t)NH * D_DIM * D_DIM * sizeof(ushort_t);      // 4 MB
  const size_t SZ_Q = (size_t)NB * NH * T_DIM * D_DIM * sizeof(ushort_t); // 33.5 MB
  const size_t SZ_SB = 136ull * SLOT_F * sizeof(float) * NH;              // 71.3 MB/batch
  const size_t FIXED = 3 * SZ_H + 2 * SZ_A + 2 * SZ_Q;                    // 87.2 MB
  ushort_t* hhi  = (ushort_t*)(ws);
  ushort_t* hlo  = (ushort_t*)(ws + SZ_H);
  ushort_t* hT   = (ushort_t*)(ws + 2 * SZ_H);
  ushort_t* AThi = (ushort_t*)(ws + 3 * SZ_H);
  ushort_t* ATlo = (ushort_t*)(ws + 3 * SZ_H + SZ_A);
  ushort_t* Qhi  = (ushort_t*)(ws + 3 * SZ_H + 2 * SZ_A);
  ushort_t* Qlo  = (ushort_t*)(ws + 3 * SZ_H + 2 * SZ_A + SZ_Q);
  float*    Sbuf = (float*)   (ws + FIXED);

  // process both batches at once if the packed S for both fits, else per batch
  int nbc = (FIXED + 2 * SZ_SB <= ws_size) ? 2 : 1;

  split_h_kernel<<<512, 256, 0, stream>>>(h, hhi, hlo, hT);
  split_AT_kernel<<<512, 256, 0, stream>>>(A, AThi, ATlo);
  qgemm_kernel<<<1024, 256, 0, stream>>>(hhi, hlo, AThi, ATlo, Qhi, Qlo);
  for (int b0 = 0; b0 < NB; b0 += nbc) {
    sgemm_kernel<<<nbc * 8 * 136, 256, 0, stream>>>(Qhi, Qlo, hhi, hlo, Sbuf, b0, nbc);
    softmax_kernel<<<nbc * 8 * 2048, 256, 0, stream>>>(Sbuf, nbc);
    pv_kernel<<<nbc * 512, 256, 0, stream>>>((const ushort_t*)Sbuf, hT, out, b0, nbc);
  }
}